// Round 5
// baseline (348.762 us; speedup 1.0000x reference)
//
#include <hip/hip_runtime.h>
#include <hip/hip_bf16.h>
#include <cstdint>
#include <cstddef>

#define NTOKS  2048
#define DMODEL 1024
#define DFFN   4096
#define NEXP   8

typedef __attribute__((ext_vector_type(8))) short short8;
typedef __attribute__((ext_vector_type(4))) float f32x4;
typedef __attribute__((ext_vector_type(4))) unsigned short u16x4;
typedef __attribute__((ext_vector_type(8))) unsigned short u16x8;

// ---------------- workspace layout ----------------
static constexpr size_t alignup(size_t x) { return (x + 255) & ~(size_t)255; }
static constexpr size_t OFF_XB   = 0;                                            // (NTOKS+1) x DMODEL bf16 (last row zeros)
static constexpr size_t OFF_CNT  = alignup(OFF_XB + (size_t)(NTOKS + 1) * DMODEL * 2);
static constexpr size_t OFF_OFFS = OFF_CNT + 256;
static constexpr size_t OFF_TOKE = OFF_OFFS + 256;                               // NTOKS*2 int
static constexpr size_t OFF_TOKT = OFF_TOKE + (size_t)NTOKS * 2 * 4;             // NTOKS*2 int
static constexpr size_t OFF_TOKS = OFF_TOKT + (size_t)NTOKS * 2 * 4;             // NTOKS*2 float
static constexpr size_t OFF_CAP  = alignup(OFF_TOKS + (size_t)NTOKS * 2 * 4);    // NEXP*NTOKS int
static constexpr size_t OFF_H    = alignup(OFF_CAP + (size_t)NEXP * NTOKS * 4);  // (4096+128) x DFFN bf16
static constexpr size_t OFF_Y    = alignup(OFF_H + (size_t)(NTOKS * 2 + 128) * DFFN * 2); // 2 slabs x 4096 x DMODEL f32
static constexpr size_t OFF_WB   = alignup(OFF_Y + (size_t)2 * NTOKS * 2 * DMODEL * 4);  // E*D*DFF bf16 (reused W1T then W2T)

__device__ inline unsigned short f2bf(float f) {
  __hip_bfloat16 h = __float2bfloat16(f);
  return __builtin_bit_cast(unsigned short, h);
}

__device__ inline void gload16(const void* g, void* l) {
  __builtin_amdgcn_global_load_lds((const __attribute__((address_space(1))) unsigned int*)g,
                                   (__attribute__((address_space(3))) unsigned int*)l, 16, 0, 0);
}

// ---------------- kernel 1: x f32 -> bf16 (+zero row), zero counts ----------------
__global__ __launch_bounds__(256) void k_convert(const float* __restrict__ x,
                                                 unsigned short* __restrict__ xb,
                                                 int* __restrict__ cnt) {
  if (blockIdx.x == 0 && threadIdx.x < NEXP) cnt[threadIdx.x] = 0;
  size_t base = ((size_t)blockIdx.x * 256 + threadIdx.x) * 8;
  const size_t total = (size_t)(NTOKS + 1) * DMODEL;
  if (base >= total) return;
  u16x8 o;
  if (base < (size_t)NTOKS * DMODEL) {
    f32x4 a = *(const f32x4*)(x + base);
    f32x4 b = *(const f32x4*)(x + base + 4);
#pragma unroll
    for (int j = 0; j < 4; ++j) { o[j] = f2bf(a[j]); o[4 + j] = f2bf(b[j]); }
  } else {
#pragma unroll
    for (int j = 0; j < 8; ++j) o[j] = 0;
  }
  *(u16x8*)(xb + base) = o;
}

// ---------------- weight transpose+convert: W[e][R][C] f32 -> WT[e][C][R] bf16 ----------------
template <int R, int C>
__global__ __launch_bounds__(256) void k_transconv(const float* __restrict__ W,
                                                   unsigned short* __restrict__ WT) {
  __shared__ unsigned short T[64][66];   // stride 66 shorts: odd bank step, 4B-aligned pairs
  const int e = blockIdx.z;
  const int c0 = blockIdx.x * 64, r0 = blockIdx.y * 64;
  const float* Wp = W + (size_t)e * R * C;
  unsigned short* Tp = WT + (size_t)e * R * C;
  const int tid = threadIdx.x;
  const int rr = tid >> 4, cc = (tid & 15) << 2;
#pragma unroll
  for (int i = 0; i < 4; ++i) {
    int r = rr + (i << 4);
    f32x4 v = *(const f32x4*)(Wp + (size_t)(r0 + r) * C + c0 + cc);
    T[r][cc]     = f2bf(v[0]);
    T[r][cc + 1] = f2bf(v[1]);
    T[r][cc + 2] = f2bf(v[2]);
    T[r][cc + 3] = f2bf(v[3]);
  }
  __syncthreads();
  const int c = tid >> 2, kc = (tid & 3) << 4;
  u16x8 o0, o1;
#pragma unroll
  for (int i = 0; i < 8; ++i) { o0[i] = T[kc + i][c]; o1[i] = T[kc + 8 + i][c]; }
  unsigned short* dst = Tp + (size_t)(c0 + c) * R + r0 + kc;
  *(u16x8*)(dst) = o0;
  *(u16x8*)(dst + 8) = o1;
}

// ---------------- kernel 2: gate (one wave per token) ----------------
__global__ __launch_bounds__(256) void k_gate(const float* __restrict__ x,
                                              const float* __restrict__ Wg,
                                              const float* __restrict__ bg,
                                              int* __restrict__ cnt,
                                              int* __restrict__ tok_e,
                                              int* __restrict__ tok_t,
                                              float* __restrict__ tok_s,
                                              int* __restrict__ cap) {
  const int w = threadIdx.x >> 6, lane = threadIdx.x & 63;
  const int n = blockIdx.x * 4 + w;
  float acc[8];
#pragma unroll
  for (int e = 0; e < 8; ++e) acc[e] = 0.f;
  const float* xr = x + (size_t)n * DMODEL;
#pragma unroll 4
  for (int it = 0; it < DMODEL / 64; ++it) {
    int d = it * 64 + lane;
    float xv = xr[d];
    f32x4 w0 = *(const f32x4*)(Wg + d * 8);
    f32x4 w1 = *(const f32x4*)(Wg + d * 8 + 4);
#pragma unroll
    for (int j = 0; j < 4; ++j) { acc[j] += xv * w0[j]; acc[4 + j] += xv * w1[j]; }
  }
#pragma unroll
  for (int e = 0; e < 8; ++e)
#pragma unroll
    for (int off = 32; off; off >>= 1) acc[e] += __shfl_xor(acc[e], off, 64);
  if (lane == 0) {
    float l[8];
#pragma unroll
    for (int e = 0; e < 8; ++e) l[e] = acc[e] + bg[e];
    int i0 = 0; float v0 = l[0];
#pragma unroll
    for (int e = 1; e < 8; ++e) if (l[e] > v0) { v0 = l[e]; i0 = e; }
    int i1 = (i0 == 0) ? 1 : 0; float v1 = l[i1];
#pragma unroll
    for (int e = 0; e < 8; ++e) if (e != i0 && l[e] > v1) { v1 = l[e]; i1 = e; }
    float t = expf(v1 - v0);
    float inv = 1.f / (1.f + t);
    float s0 = inv, s1 = t * inv;
    int t0 = atomicAdd(&cnt[i0], 1);
    int t1 = atomicAdd(&cnt[i1], 1);
    cap[i0 * NTOKS + t0] = n;
    cap[i1 * NTOKS + t1] = n;
    tok_e[2 * n] = i0; tok_e[2 * n + 1] = i1;
    tok_t[2 * n] = t0; tok_t[2 * n + 1] = t1;
    tok_s[2 * n] = s0; tok_s[2 * n + 1] = s1;
  }
}

// ---------------- kernel 3: offsets = exclusive scan of counts ----------------
__global__ void k_scan(const int* __restrict__ cnt, int* __restrict__ offs) {
  if (threadIdx.x == 0) {
    int s = 0;
#pragma unroll
    for (int e = 0; e < NEXP; ++e) { offs[e] = s; s += cnt[e]; }
  }
}

// ---------------- grouped GEMM: BM=128, BK=64, double-buffered, all-bf16 ----------------
// Round-3 proven loop (single __syncthreads per step, compiler-scheduled) +
// XCD-grouping remap (N-blocks sharing an (e,tile) A-panel -> same XCD L2) +
// optional split-K (blockIdx.z picks K-chunk; partial f32 slabs summed in combine).
template <int KTOT, int NTOT, int BN, bool FIRST, int KSPLIT>
__global__ __launch_bounds__(256) void k_gemm(const unsigned short* __restrict__ Asrc,
                                              const unsigned short* __restrict__ Bsrc,
                                              const float* __restrict__ bias,
                                              const int* __restrict__ cnt,
                                              const int* __restrict__ offs,
                                              const int* __restrict__ cap,
                                              unsigned short* __restrict__ hout,
                                              float* __restrict__ yout) {
  constexpr int NBLK = NTOT / BN;      // n-blocks per group, power of 2
  constexpr int KCH = KTOT / KSPLIT;   // K per chunk
  constexpr int NT = KCH / 64;
  // --- XCD-grouping remap within the z-plane ---
  const int f = blockIdx.y * NBLK + blockIdx.x;
  const int xcd = f & 7, q = f >> 3;
  const int j = q % NBLK, gq = q / NBLK;
  const int g = gq * 8 + xcd;          // 0..127 = e*16 + tile
  const int e = g >> 4, tile = g & 15;
  const int c = cnt[e];
  const int t0 = tile * 128;
  if (t0 >= c) return;
  const int base = offs[e] + t0;
  const int n0 = j * BN;
  const int kb = blockIdx.z * KCH;     // K-chunk base

  const int tid = threadIdx.x, w = tid >> 6, lane = tid & 63;
  const int l15 = lane & 15, lq = lane >> 4;
  constexpr int MR = 4;
  constexpr int NR = BN / 32;          // 4 (BN=128) or 2 (BN=64)
  constexpr int BROUNDS = BN / 32;
  const int wr = w >> 1, wc = w & 1;

  __shared__ unsigned short As[2][128 * 64];
  __shared__ unsigned short Bs[2][BN * 64];

  // staging source pointers: round r covers rows r*32 + (tid>>3), chunk tid&7 (16B),
  // fetching global chunk (tid&7) ^ (row&7)  [inverse swizzle on source]
  const int rl = tid >> 3;
  const int sw = ((tid & 7) ^ (rl & 7)) << 3;    // shorts
  const unsigned short* aptr[4];
#pragma unroll
  for (int r = 0; r < 4; ++r) {
    int row = r * 32 + rl;
    size_t gr;
    if constexpr (FIRST) gr = (size_t)((t0 + row < c) ? cap[e * NTOKS + t0 + row] : NTOKS);
    else                 gr = (size_t)(base + row);
    aptr[r] = Asrc + gr * (size_t)KTOT + kb + sw;
  }
  const unsigned short* Be = Bsrc + (size_t)e * ((size_t)KTOT * NTOT);
  const unsigned short* bptr[BROUNDS];
#pragma unroll
  for (int r = 0; r < BROUNDS; ++r)
    bptr[r] = Be + (size_t)(n0 + r * 32 + rl) * KTOT + kb + sw;

  auto stageA = [&](int k0, int b) {
#pragma unroll
    for (int r = 0; r < 4; ++r)
      gload16(aptr[r] + k0, &As[b][(r * 32 + (w << 3)) << 6]);
  };
  auto stageB = [&](int k0, int b) {
#pragma unroll
    for (int r = 0; r < BROUNDS; ++r)
      gload16(bptr[r] + k0, &Bs[b][(r * 32 + (w << 3)) << 6]);
  };

  f32x4 acc[MR][NR] = {};

  stageA(0, 0);
  stageB(0, 0);
  __syncthreads();

  int buf = 0;
  for (int t = 0; t < NT; ++t) {
    const int nxt = buf ^ 1;
    if (t + 1 < NT) { stageA((t + 1) << 6, nxt); stageB((t + 1) << 6, nxt); }

    short8 a0[MR], a1[MR], b0[NR], b1[NR];
    const int sw0 = (lq ^ (l15 & 7)) << 3;        // kk=0 slot (shorts); kk=1 = sw0^32
#pragma unroll
    for (int m = 0; m < MR; ++m) {
      const unsigned short* ab = &As[buf][(wr * 64 + m * 16 + l15) << 6];
      a0[m] = *(const short8*)&ab[sw0];
      a1[m] = *(const short8*)&ab[sw0 ^ 32];
    }
#pragma unroll
    for (int nn = 0; nn < NR; ++nn) {
      const unsigned short* bb = &Bs[buf][(wc * (BN / 2) + nn * 16 + l15) << 6];
      b0[nn] = *(const short8*)&bb[sw0];
      b1[nn] = *(const short8*)&bb[sw0 ^ 32];
    }
#pragma unroll
    for (int m = 0; m < MR; ++m)
#pragma unroll
      for (int nn = 0; nn < NR; ++nn) {
        acc[m][nn] = __builtin_amdgcn_mfma_f32_16x16x32_bf16(a0[m], b0[nn], acc[m][nn], 0, 0, 0);
        acc[m][nn] = __builtin_amdgcn_mfma_f32_16x16x32_bf16(a1[m], b1[nn], acc[m][nn], 0, 0, 0);
      }

    __syncthreads();
    buf = nxt;
  }

  // --- epilogue ---
  if constexpr (FIRST) {
    const float* be = bias + (size_t)e * NTOT;
#pragma unroll
    for (int m = 0; m < MR; ++m) {
#pragma unroll
      for (int q2 = 0; q2 < 4; ++q2) {
        int row = wr * 64 + m * 16 + lq * 4 + q2;
        if (t0 + row < c) {
          unsigned short* hr = hout + (size_t)(base + row) * NTOT;
#pragma unroll
          for (int nn = 0; nn < NR; ++nn) {
            int col = n0 + wc * (BN / 2) + nn * 16 + l15;
            float v = acc[m][nn][q2] + be[col];
            v = v > 0.f ? v : 0.f;
            hr[col] = f2bf(v);
          }
        }
      }
    }
  } else {
    float* yz = yout + (size_t)blockIdx.z * NTOKS * 2 * DMODEL;
#pragma unroll
    for (int m = 0; m < MR; ++m) {
#pragma unroll
      for (int q2 = 0; q2 < 4; ++q2) {
        int row = wr * 64 + m * 16 + lq * 4 + q2;
        if (t0 + row < c) {
          float* yr = yz + (size_t)(base + row) * NTOT;
#pragma unroll
          for (int nn = 0; nn < NR; ++nn) {
            int col = n0 + wc * (BN / 2) + nn * 16 + l15;
            yr[col] = acc[m][nn][q2];
          }
        }
      }
    }
  }
}

// ---------------- kernel 6: combine (one block per token; sums split-K slabs) ----------------
__global__ __launch_bounds__(256) void k_combine(const float* __restrict__ y,
                                                 const float* __restrict__ b2,
                                                 const int* __restrict__ tok_e,
                                                 const int* __restrict__ tok_t,
                                                 const float* __restrict__ tok_s,
                                                 const int* __restrict__ offs,
                                                 float* __restrict__ out) {
  const int n = blockIdx.x, t = threadIdx.x;
  const float* y1 = y + (size_t)NTOKS * 2 * DMODEL;
  const int e0 = tok_e[2 * n], e1 = tok_e[2 * n + 1];
  const int s0i = offs[e0] + tok_t[2 * n];
  const int s1i = offs[e1] + tok_t[2 * n + 1];
  const float sc0 = tok_s[2 * n], sc1 = tok_s[2 * n + 1];
  f32x4 v0 = *(const f32x4*)(y + (size_t)s0i * DMODEL + t * 4);
  f32x4 u0 = *(const f32x4*)(y1 + (size_t)s0i * DMODEL + t * 4);
  f32x4 v1 = *(const f32x4*)(y + (size_t)s1i * DMODEL + t * 4);
  f32x4 u1 = *(const f32x4*)(y1 + (size_t)s1i * DMODEL + t * 4);
  f32x4 c0 = *(const f32x4*)(b2 + (size_t)e0 * DMODEL + t * 4);
  f32x4 c1 = *(const f32x4*)(b2 + (size_t)e1 * DMODEL + t * 4);
  f32x4 r = sc0 * ((v0 + u0) + c0) + sc1 * ((v1 + u1) + c1);
  *(f32x4*)(out + (size_t)n * DMODEL + t * 4) = r;
}

extern "C" void kernel_launch(void* const* d_in, const int* in_sizes, int n_in,
                              void* d_out, int out_size, void* d_ws, size_t ws_size,
                              hipStream_t stream) {
  const float* x  = (const float*)d_in[0];
  const float* Wg = (const float*)d_in[1];
  const float* bg = (const float*)d_in[2];
  const float* W1 = (const float*)d_in[3];
  const float* b1 = (const float*)d_in[4];
  const float* W2 = (const float*)d_in[5];
  const float* b2 = (const float*)d_in[6];
  float* out = (float*)d_out;

  char* ws = (char*)d_ws;
  unsigned short* xb = (unsigned short*)(ws + OFF_XB);
  int*   cnt   = (int*)(ws + OFF_CNT);
  int*   offs  = (int*)(ws + OFF_OFFS);
  int*   tok_e = (int*)(ws + OFF_TOKE);
  int*   tok_t = (int*)(ws + OFF_TOKT);
  float* tok_s = (float*)(ws + OFF_TOKS);
  int*   cap   = (int*)(ws + OFF_CAP);
  unsigned short* h  = (unsigned short*)(ws + OFF_H);
  float* y = (float*)(ws + OFF_Y);
  unsigned short* wb = (unsigned short*)(ws + OFF_WB);   // reused: W1T then W2T

  const int convBlocks = (int)(((size_t)(NTOKS + 1) * DMODEL / 8 + 255) / 256);
  k_convert<<<convBlocks, 256, 0, stream>>>(x, xb, cnt);
  k_gate<<<NTOKS / 4, 256, 0, stream>>>(x, Wg, bg, cnt, tok_e, tok_t, tok_s, cap);
  k_scan<<<1, 64, 0, stream>>>(cnt, offs);

  // W1 [E][D][DFF] -> wb [E][DFF][D] bf16
  k_transconv<DMODEL, DFFN><<<dim3(DFFN / 64, DMODEL / 64, NEXP), 256, 0, stream>>>(W1, wb);
  k_gemm<DMODEL, DFFN, 128, true, 1><<<dim3(DFFN / 128, NEXP * 16, 1), 256, 0, stream>>>(
      xb, wb, b1, cnt, offs, cap, h, nullptr);

  // W2 [E][DFF][D] -> wb [E][D][DFF] bf16 (reuse buffer)
  k_transconv<DFFN, DMODEL><<<dim3(DMODEL / 64, DFFN / 64, NEXP), 256, 0, stream>>>(W2, wb);
  k_gemm<DFFN, DMODEL, 64, false, 2><<<dim3(DMODEL / 64, NEXP * 16, 2), 256, 0, stream>>>(
      h, wb, nullptr, cnt, offs, cap, nullptr, y);

  k_combine<<<NTOKS, 256, 0, stream>>>(y, b2, tok_e, tok_t, tok_s, offs, out);
}

// Round 6
// 282.593 us; speedup vs baseline: 1.2341x; 1.2341x over previous
//
#include <hip/hip_runtime.h>
#include <hip/hip_bf16.h>
#include <cstdint>
#include <cstddef>

#define NTOKS  2048
#define DMODEL 1024
#define DFFN   4096
#define NEXP   8
#define TSLOTS 40   // max live M-tiles: sum_e ceil(c_e/128) <= 32+7

typedef __attribute__((ext_vector_type(8))) short short8;
typedef __attribute__((ext_vector_type(4))) float f32x4;
typedef __attribute__((ext_vector_type(4))) unsigned short u16x4;
typedef __attribute__((ext_vector_type(8))) unsigned short u16x8;

// ---------------- workspace layout ----------------
static constexpr size_t alignup(size_t x) { return (x + 255) & ~(size_t)255; }
static constexpr size_t OFF_XB   = 0;                                            // (NTOKS+1) x DMODEL bf16 (last row zeros)
static constexpr size_t OFF_CNT  = alignup(OFF_XB + (size_t)(NTOKS + 1) * DMODEL * 2);
static constexpr size_t OFF_OFFS = OFF_CNT + 256;
static constexpr size_t OFF_TOKE = OFF_OFFS + 256;                               // NTOKS*2 int
static constexpr size_t OFF_TOKT = OFF_TOKE + (size_t)NTOKS * 2 * 4;             // NTOKS*2 int
static constexpr size_t OFF_TOKS = OFF_TOKT + (size_t)NTOKS * 2 * 4;             // NTOKS*2 float
static constexpr size_t OFF_TI   = alignup(OFF_TOKS + (size_t)NTOKS * 2 * 4);    // TSLOTS int2
static constexpr size_t OFF_CAP  = alignup(OFF_TI + 512);                        // NEXP*NTOKS int
static constexpr size_t OFF_H    = alignup(OFF_CAP + (size_t)NEXP * NTOKS * 4);  // (4096+128) x DFFN bf16
static constexpr size_t OFF_Y    = alignup(OFF_H + (size_t)(NTOKS * 2 + 128) * DFFN * 2); // 2 slabs x 4096 x DMODEL f32
static constexpr size_t OFF_WB   = alignup(OFF_Y + (size_t)2 * NTOKS * 2 * DMODEL * 4);  // E*D*DFF bf16 (reused W1T then W2T)

__device__ inline unsigned short f2bf(float f) {
  __hip_bfloat16 h = __float2bfloat16(f);
  return __builtin_bit_cast(unsigned short, h);
}

__device__ inline void gload16(const void* g, void* l) {
  __builtin_amdgcn_global_load_lds((const __attribute__((address_space(1))) unsigned int*)g,
                                   (__attribute__((address_space(3))) unsigned int*)l, 16, 0, 0);
}

// ---------------- kernel 1: x f32 -> bf16 (+zero row), zero counts ----------------
__global__ __launch_bounds__(256) void k_convert(const float* __restrict__ x,
                                                 unsigned short* __restrict__ xb,
                                                 int* __restrict__ cnt) {
  if (blockIdx.x == 0 && threadIdx.x < NEXP) cnt[threadIdx.x] = 0;
  size_t base = ((size_t)blockIdx.x * 256 + threadIdx.x) * 8;
  const size_t total = (size_t)(NTOKS + 1) * DMODEL;
  if (base >= total) return;
  u16x8 o;
  if (base < (size_t)NTOKS * DMODEL) {
    f32x4 a = *(const f32x4*)(x + base);
    f32x4 b = *(const f32x4*)(x + base + 4);
#pragma unroll
    for (int j = 0; j < 4; ++j) { o[j] = f2bf(a[j]); o[4 + j] = f2bf(b[j]); }
  } else {
#pragma unroll
    for (int j = 0; j < 8; ++j) o[j] = 0;
  }
  *(u16x8*)(xb + base) = o;
}

// ---------------- weight transpose+convert: W[e][R][C] f32 -> WT[e][C][R] bf16 ----------------
template <int R, int C>
__global__ __launch_bounds__(256) void k_transconv(const float* __restrict__ W,
                                                   unsigned short* __restrict__ WT) {
  __shared__ unsigned short T[64][66];   // stride 66 shorts: odd bank step, 4B-aligned pairs
  const int e = blockIdx.z;
  const int c0 = blockIdx.x * 64, r0 = blockIdx.y * 64;
  const float* Wp = W + (size_t)e * R * C;
  unsigned short* Tp = WT + (size_t)e * R * C;
  const int tid = threadIdx.x;
  const int rr = tid >> 4, cc = (tid & 15) << 2;
#pragma unroll
  for (int i = 0; i < 4; ++i) {
    int r = rr + (i << 4);
    f32x4 v = *(const f32x4*)(Wp + (size_t)(r0 + r) * C + c0 + cc);
    T[r][cc]     = f2bf(v[0]);
    T[r][cc + 1] = f2bf(v[1]);
    T[r][cc + 2] = f2bf(v[2]);
    T[r][cc + 3] = f2bf(v[3]);
  }
  __syncthreads();
  const int c = tid >> 2, kc = (tid & 3) << 4;
  u16x8 o0, o1;
#pragma unroll
  for (int i = 0; i < 8; ++i) { o0[i] = T[kc + i][c]; o1[i] = T[kc + 8 + i][c]; }
  unsigned short* dst = Tp + (size_t)(c0 + c) * R + r0 + kc;
  *(u16x8*)(dst) = o0;
  *(u16x8*)(dst + 8) = o1;
}

// ---------------- kernel 2: gate (one wave per token) ----------------
__global__ __launch_bounds__(256) void k_gate(const float* __restrict__ x,
                                              const float* __restrict__ Wg,
                                              const float* __restrict__ bg,
                                              int* __restrict__ cnt,
                                              int* __restrict__ tok_e,
                                              int* __restrict__ tok_t,
                                              float* __restrict__ tok_s,
                                              int* __restrict__ cap) {
  const int w = threadIdx.x >> 6, lane = threadIdx.x & 63;
  const int n = blockIdx.x * 4 + w;
  float acc[8];
#pragma unroll
  for (int e = 0; e < 8; ++e) acc[e] = 0.f;
  const float* xr = x + (size_t)n * DMODEL;
#pragma unroll 4
  for (int it = 0; it < DMODEL / 64; ++it) {
    int d = it * 64 + lane;
    float xv = xr[d];
    f32x4 w0 = *(const f32x4*)(Wg + d * 8);
    f32x4 w1 = *(const f32x4*)(Wg + d * 8 + 4);
#pragma unroll
    for (int j = 0; j < 4; ++j) { acc[j] += xv * w0[j]; acc[4 + j] += xv * w1[j]; }
  }
#pragma unroll
  for (int e = 0; e < 8; ++e)
#pragma unroll
    for (int off = 32; off; off >>= 1) acc[e] += __shfl_xor(acc[e], off, 64);
  if (lane == 0) {
    float l[8];
#pragma unroll
    for (int e = 0; e < 8; ++e) l[e] = acc[e] + bg[e];
    int i0 = 0; float v0 = l[0];
#pragma unroll
    for (int e = 1; e < 8; ++e) if (l[e] > v0) { v0 = l[e]; i0 = e; }
    int i1 = (i0 == 0) ? 1 : 0; float v1 = l[i1];
#pragma unroll
    for (int e = 0; e < 8; ++e) if (e != i0 && l[e] > v1) { v1 = l[e]; i1 = e; }
    float t = expf(v1 - v0);
    float inv = 1.f / (1.f + t);
    float s0 = inv, s1 = t * inv;
    int t0 = atomicAdd(&cnt[i0], 1);
    int t1 = atomicAdd(&cnt[i1], 1);
    cap[i0 * NTOKS + t0] = n;
    cap[i1 * NTOKS + t1] = n;
    tok_e[2 * n] = i0; tok_e[2 * n + 1] = i1;
    tok_t[2 * n] = t0; tok_t[2 * n + 1] = t1;
    tok_s[2 * n] = s0; tok_s[2 * n + 1] = s1;
  }
}

// ---------------- kernel 3: offsets + dense live-tile table ----------------
__global__ void k_scan(const int* __restrict__ cnt, int* __restrict__ offs,
                       int2* __restrict__ tinfo) {
  if (threadIdx.x == 0) {
    int s = 0;
#pragma unroll
    for (int e = 0; e < NEXP; ++e) { offs[e] = s; s += cnt[e]; }
    int ns = 0;
    for (int e = 0; e < NEXP; ++e)
      for (int t = 0; t * 128 < cnt[e]; ++t) { tinfo[ns] = make_int2(e, t * 128); ++ns; }
    for (; ns < TSLOTS; ++ns) tinfo[ns] = make_int2(-1, 0);
  }
}

// ---------------- grouped GEMM: BM=128, BK=32, double-buffered, all-bf16 ----------------
// m97-class geometry: 32KB (BN=128) / 24KB (BN=64) LDS -> 4-6 blocks/CU; latency hidden
// by cross-block wave overlap. Live M-tiles come from the dense tinfo table (no dead
// blocks). Both operands staged via global_load_lds(16B) with XOR-preswizzled per-lane
// SOURCE + linear LDS dest. LDS row = 32 shorts (64B), 4 chunks of 16B; cell (row,slot)
// holds global chunk slot ^ x(row), x(row) = (row ^ (row>>2)) & 3 -> fragment b128 reads
// are 2-way bank-aliased (free). Optional split-K via blockIdx.z (f32 slabs, fixed-order
// sum in combine -> deterministic).
template <int KTOT, int NTOT, int BN, bool FIRST, int KSPLIT>
__global__ __launch_bounds__(256) void k_gemm(const unsigned short* __restrict__ Asrc,
                                              const unsigned short* __restrict__ Bsrc,
                                              const float* __restrict__ bias,
                                              const int* __restrict__ cnt,
                                              const int* __restrict__ offs,
                                              const int2* __restrict__ tinfo,
                                              const int* __restrict__ cap,
                                              unsigned short* __restrict__ hout,
                                              float* __restrict__ yout) {
  const int2 ti = tinfo[blockIdx.y];
  if (ti.x < 0) return;
  const int e = ti.x, t0 = ti.y;
  const int c = cnt[e];
  const int base = offs[e] + t0;
  const int n0 = blockIdx.x * BN;
  constexpr int KCH = KTOT / KSPLIT;
  constexpr int NT = KCH / 32;
  const int kb = blockIdx.z * KCH;

  const int tid = threadIdx.x, w = tid >> 6, lane = tid & 63;
  const int l15 = lane & 15, lq = lane >> 4;
  constexpr int MR = 4;
  constexpr int NR = BN / 32;          // 4 (BN=128) or 2 (BN=64)
  constexpr int BR = BN / 64;          // B staging rounds: 2 or 1
  const int wr = w >> 1, wc = w & 1;

  __shared__ unsigned short As[2][128 * 32];
  __shared__ unsigned short Bs[2][BN * 32];

  // staging: lane covers (row = 64*r + (tid>>2), chunk = tid&3); source fetches global
  // chunk (tid&3) ^ x(row); x(64r+rl) == (rl ^ (rl>>2)) & 3
  const int rl = tid >> 2;
  const int sw = (((tid & 3) ^ (rl & 3) ^ ((rl >> 2) & 3)) << 3);   // shorts
  const unsigned short* aptr[2];
#pragma unroll
  for (int r = 0; r < 2; ++r) {
    int row = r * 64 + rl;
    size_t gr;
    if constexpr (FIRST) gr = (size_t)((t0 + row < c) ? cap[e * NTOKS + t0 + row] : NTOKS);
    else                 gr = (size_t)(base + row);
    aptr[r] = Asrc + gr * (size_t)KTOT + kb + sw;
  }
  const unsigned short* Be = Bsrc + (size_t)e * ((size_t)KTOT * NTOT);
  const unsigned short* bptr[BR];
#pragma unroll
  for (int r = 0; r < BR; ++r)
    bptr[r] = Be + (size_t)(n0 + r * 64 + rl) * KTOT + kb + sw;

  auto stageA = [&](int k0, int b) {
#pragma unroll
    for (int r = 0; r < 2; ++r)
      gload16(aptr[r] + k0, &As[b][(r * 64 + w * 16) << 5]);
  };
  auto stageB = [&](int k0, int b) {
#pragma unroll
    for (int r = 0; r < BR; ++r)
      gload16(bptr[r] + k0, &Bs[b][(r * 64 + w * 16) << 5]);
  };

  f32x4 acc[MR][NR] = {};

  stageA(0, 0);
  stageB(0, 0);
  __syncthreads();

  int buf = 0;
  for (int t = 0; t < NT; ++t) {
    const int nxt = buf ^ 1;
    if (t + 1 < NT) { stageA((t + 1) * 32, nxt); stageB((t + 1) * 32, nxt); }

    short8 a[MR], b[NR];
    const int sw0 = ((lq ^ (l15 & 3) ^ ((l15 >> 2) & 3)) << 3);     // shorts
#pragma unroll
    for (int m = 0; m < MR; ++m)
      a[m] = *(const short8*)&As[buf][((wr * 64 + m * 16 + l15) << 5) + sw0];
#pragma unroll
    for (int nn = 0; nn < NR; ++nn)
      b[nn] = *(const short8*)&Bs[buf][((wc * (BN / 2) + nn * 16 + l15) << 5) + sw0];
#pragma unroll
    for (int m = 0; m < MR; ++m)
#pragma unroll
      for (int nn = 0; nn < NR; ++nn)
        acc[m][nn] = __builtin_amdgcn_mfma_f32_16x16x32_bf16(a[m], b[nn], acc[m][nn], 0, 0, 0);

    __syncthreads();
    buf = nxt;
  }

  // --- epilogue ---
  if constexpr (FIRST) {
    const float* be = bias + (size_t)e * NTOT;
#pragma unroll
    for (int m = 0; m < MR; ++m) {
#pragma unroll
      for (int q2 = 0; q2 < 4; ++q2) {
        int row = wr * 64 + m * 16 + lq * 4 + q2;
        if (t0 + row < c) {
          unsigned short* hr = hout + (size_t)(base + row) * NTOT;
#pragma unroll
          for (int nn = 0; nn < NR; ++nn) {
            int col = n0 + wc * (BN / 2) + nn * 16 + l15;
            float v = acc[m][nn][q2] + be[col];
            v = v > 0.f ? v : 0.f;
            hr[col] = f2bf(v);
          }
        }
      }
    }
  } else {
    float* yz = yout + (size_t)blockIdx.z * NTOKS * 2 * DMODEL;
#pragma unroll
    for (int m = 0; m < MR; ++m) {
#pragma unroll
      for (int q2 = 0; q2 < 4; ++q2) {
        int row = wr * 64 + m * 16 + lq * 4 + q2;
        if (t0 + row < c) {
          float* yr = yz + (size_t)(base + row) * NTOT;
#pragma unroll
          for (int nn = 0; nn < NR; ++nn) {
            int col = n0 + wc * (BN / 2) + nn * 16 + l15;
            yr[col] = acc[m][nn][q2];
          }
        }
      }
    }
  }
}

// ---------------- kernel 6: combine (one block per token; sums split-K slabs) ----------------
__global__ __launch_bounds__(256) void k_combine(const float* __restrict__ y,
                                                 const float* __restrict__ b2,
                                                 const int* __restrict__ tok_e,
                                                 const int* __restrict__ tok_t,
                                                 const float* __restrict__ tok_s,
                                                 const int* __restrict__ offs,
                                                 float* __restrict__ out) {
  const int n = blockIdx.x, t = threadIdx.x;
  const float* y1 = y + (size_t)NTOKS * 2 * DMODEL;
  const int e0 = tok_e[2 * n], e1 = tok_e[2 * n + 1];
  const int s0i = offs[e0] + tok_t[2 * n];
  const int s1i = offs[e1] + tok_t[2 * n + 1];
  const float sc0 = tok_s[2 * n], sc1 = tok_s[2 * n + 1];
  f32x4 v0 = *(const f32x4*)(y + (size_t)s0i * DMODEL + t * 4);
  f32x4 u0 = *(const f32x4*)(y1 + (size_t)s0i * DMODEL + t * 4);
  f32x4 v1 = *(const f32x4*)(y + (size_t)s1i * DMODEL + t * 4);
  f32x4 u1 = *(const f32x4*)(y1 + (size_t)s1i * DMODEL + t * 4);
  f32x4 c0 = *(const f32x4*)(b2 + (size_t)e0 * DMODEL + t * 4);
  f32x4 c1 = *(const f32x4*)(b2 + (size_t)e1 * DMODEL + t * 4);
  f32x4 r = sc0 * ((v0 + u0) + c0) + sc1 * ((v1 + u1) + c1);
  *(f32x4*)(out + (size_t)n * DMODEL + t * 4) = r;
}

extern "C" void kernel_launch(void* const* d_in, const int* in_sizes, int n_in,
                              void* d_out, int out_size, void* d_ws, size_t ws_size,
                              hipStream_t stream) {
  const float* x  = (const float*)d_in[0];
  const float* Wg = (const float*)d_in[1];
  const float* bg = (const float*)d_in[2];
  const float* W1 = (const float*)d_in[3];
  const float* b1 = (const float*)d_in[4];
  const float* W2 = (const float*)d_in[5];
  const float* b2 = (const float*)d_in[6];
  float* out = (float*)d_out;

  char* ws = (char*)d_ws;
  unsigned short* xb = (unsigned short*)(ws + OFF_XB);
  int*   cnt   = (int*)(ws + OFF_CNT);
  int*   offs  = (int*)(ws + OFF_OFFS);
  int*   tok_e = (int*)(ws + OFF_TOKE);
  int*   tok_t = (int*)(ws + OFF_TOKT);
  float* tok_s = (float*)(ws + OFF_TOKS);
  int2*  tinfo = (int2*)(ws + OFF_TI);
  int*   cap   = (int*)(ws + OFF_CAP);
  unsigned short* h  = (unsigned short*)(ws + OFF_H);
  float* y = (float*)(ws + OFF_Y);
  unsigned short* wb = (unsigned short*)(ws + OFF_WB);   // reused: W1T then W2T

  const int convBlocks = (int)(((size_t)(NTOKS + 1) * DMODEL / 8 + 255) / 256);
  k_convert<<<convBlocks, 256, 0, stream>>>(x, xb, cnt);
  k_gate<<<NTOKS / 4, 256, 0, stream>>>(x, Wg, bg, cnt, tok_e, tok_t, tok_s, cap);
  k_scan<<<1, 64, 0, stream>>>(cnt, offs, tinfo);

  // W1 [E][D][DFF] -> wb [E][DFF][D] bf16
  k_transconv<DMODEL, DFFN><<<dim3(DFFN / 64, DMODEL / 64, NEXP), 256, 0, stream>>>(W1, wb);
  k_gemm<DMODEL, DFFN, 128, true, 1><<<dim3(DFFN / 128, TSLOTS, 1), 256, 0, stream>>>(
      xb, wb, b1, cnt, offs, tinfo, cap, h, nullptr);

  // W2 [E][DFF][D] -> wb [E][D][DFF] bf16 (reuse buffer)
  k_transconv<DFFN, DMODEL><<<dim3(DMODEL / 64, DFFN / 64, NEXP), 256, 0, stream>>>(W2, wb);
  k_gemm<DFFN, DMODEL, 64, false, 2><<<dim3(DMODEL / 64, TSLOTS, 2), 256, 0, stream>>>(
      h, wb, nullptr, cnt, offs, tinfo, cap, nullptr, y);

  k_combine<<<NTOKS, 256, 0, stream>>>(y, b2, tok_e, tok_t, tok_s, offs, out);
}